// Round 13
// baseline (943.406 us; speedup 1.0000x reference)
//
#include <hip/hip_runtime.h>
#include <math.h>

#define BATCH     512
#define NBLK      256                    // 2 batch elements per block
#define T_PAST_   360
#define T_FUT_    1800
#define IN_SZ     3
#define H_SZ      64
#define FUT_SEQ   50
#define WSPF_     34
#define MAX_STEPS (FUT_SEQ * WSPF_)      // 1700
#define T_TOT     (T_PAST_ + MAX_STEPS)  // 2060
#define NTHREADS  256
#define LOG2E     1.44269504f

typedef __fp16 h2 __attribute__((ext_vector_type(2)));

__device__ __forceinline__ h2  as_h2(int v) { return __builtin_bit_cast(h2, v); }
__device__ __forceinline__ int as_i(h2 v)   { return __builtin_bit_cast(int, v); }
__device__ __forceinline__ float rcp_(float x) { return __builtin_amdgcn_rcpf(x); }

__device__ __forceinline__ float exp2_(float x) {
#if __has_builtin(__builtin_amdgcn_exp2f)
    return __builtin_amdgcn_exp2f(x);    // raw v_exp_f32
#else
    return exp2f(x);
#endif
}

// tanh with the 2/ln2 scale fused into the exp argument (one mul + v_exp)
__device__ __forceinline__ float tanh2_(float x) {
    float a = fabsf(x);
    float e = exp2_(a * -2.885390082f);  // exp(-2a), in (0,1]
    float t = (1.0f - e) * rcp_(1.0f + e);
    return copysignf(t, x);
}

// packed-pair dot with f32 accumulate: D = a.x*b.x + a.y*b.y + c
__device__ __forceinline__ float dot2_(int a, int b, float c) {
#if __has_builtin(__builtin_amdgcn_fdot2)
    return __builtin_amdgcn_fdot2(as_h2(a), as_h2(b), c, false);
#else
    h2 av = as_h2(a), bv = as_h2(b);
    return fmaf((float)av.x, (float)bv.x, fmaf((float)av.y, (float)bv.y, c));
#endif
}

// DPP quad broadcast: every lane of a quad gets quad-lane i's value
template <int PAT>
__device__ __forceinline__ float quadb_(float v) {
    return __builtin_bit_cast(float,
        __builtin_amdgcn_update_dpp(0, __builtin_bit_cast(int, v),
                                    PAT, 0xF, 0xF, true));
}

// r12 (unit,gate) mapping x TWO elements per block (r11's in-wave dovetail),
// with x packed fp16 so LDS (~55 KB) still allows 2 blocks/CU. Chain cuts vs
// r12: h published by direct ds_write_b16 (no ds_swizzle/pack), exp arguments
// pre-scaled by 1/ln2 (raw v_exp_f32), projection moved off the time loop
// (checkpoint h stashed, projected after the loop).
__global__ __launch_bounds__(NTHREADS, 2)
void lstm_fused_kernel(const float* __restrict__ wave_input,   // [B, 360, 3]
                       const float* __restrict__ wave_future,  // [B, 1800, 3]
                       const float* __restrict__ W_ih,         // [256, 3]
                       const float* __restrict__ W_hh,         // [256, 64]
                       const float* __restrict__ b_ih,         // [256]
                       const float* __restrict__ b_hh,         // [256]
                       const float* __restrict__ W_proj,       // [64, 64]
                       const float* __restrict__ b_proj,       // [64]
                       float* __restrict__ out)                // [B, 50, 64]
{
    __shared__ __align__(16) int    x2_lds[2][T_TOT * 2];      // packed x, 33 KB
    __shared__ __align__(16) int    wp_lds[H_SZ * 33];         // packed W_proj, 8.4 KB
    __shared__ __align__(16) __fp16 h2buf[2][2][H_SZ];         // [elem][buf], 512 B
    __shared__ __align__(16) __fp16 stash[2][FUT_SEQ][H_SZ];   // checkpoints, 12.8 KB

    const int b    = blockIdx.x;        // elem A = b, elem B = b + NBLK
    const int tid  = threadIdx.x;
    const int wv   = tid >> 6;
    const int lane = tid & 63;
    const int g    = lane & 3;          // gate: 0=i 1=f 2=g 3=o
    const int u    = wv * 16 + (lane >> 2);   // hidden unit
    const int row  = g * H_SZ + u;      // gate-matrix row

    // ---- stage both x sequences, packed fp16 (one-time) ----
    {
        const float* wiA = wave_input  + (size_t)b * (T_PAST_ * IN_SZ);
        const float* wiB = wave_input  + (size_t)(b + NBLK) * (T_PAST_ * IN_SZ);
        for (int i = tid; i < T_PAST_; i += NTHREADS) {
            x2_lds[0][2*i  ] = as_i(__builtin_amdgcn_cvt_pkrtz(wiA[3*i], wiA[3*i+1]));
            x2_lds[0][2*i+1] = as_i(__builtin_amdgcn_cvt_pkrtz(wiA[3*i+2], 0.0f));
            x2_lds[1][2*i  ] = as_i(__builtin_amdgcn_cvt_pkrtz(wiB[3*i], wiB[3*i+1]));
            x2_lds[1][2*i+1] = as_i(__builtin_amdgcn_cvt_pkrtz(wiB[3*i+2], 0.0f));
        }
        const float* wfA = wave_future + (size_t)b * (T_FUT_ * IN_SZ);
        const float* wfB = wave_future + (size_t)(b + NBLK) * (T_FUT_ * IN_SZ);
        for (int i = tid; i < MAX_STEPS; i += NTHREADS) {
            int tt = T_PAST_ + i;
            x2_lds[0][2*tt  ] = as_i(__builtin_amdgcn_cvt_pkrtz(wfA[3*i], wfA[3*i+1]));
            x2_lds[0][2*tt+1] = as_i(__builtin_amdgcn_cvt_pkrtz(wfA[3*i+2], 0.0f));
            x2_lds[1][2*tt  ] = as_i(__builtin_amdgcn_cvt_pkrtz(wfB[3*i], wfB[3*i+1]));
            x2_lds[1][2*tt+1] = as_i(__builtin_amdgcn_cvt_pkrtz(wfB[3*i+2], 0.0f));
        }
    }
    // ---- W_proj rows packed fp16, stride 33 words (2-way banks = free) ----
    for (int i = tid; i < H_SZ * 32; i += NTHREADS) {
        int j = i >> 5, m = i & 31;
        wp_lds[j * 33 + m] = as_i(__builtin_amdgcn_cvt_pkrtz(
            W_proj[j * H_SZ + 2 * m], W_proj[j * H_SZ + 2 * m + 1]));
    }
    if (tid < 2 * H_SZ) h2buf[tid >> 6][0][tid & 63] = (__fp16)0.0f;  // h(0)=0

    // g-gate: tanh(x)=2*sigmoid(2x)-1 -> fold 2x into weights; all rows also
    // fold 1/ln2 so the sigmoid exp is a raw v_exp_f32 (exp2)
    const float scale = ((g == 2) ? 2.0f : 1.0f) * LOG2E;
    const float aa    = (g == 2) ? 2.0f : 1.0f;
    const float bb    = (g == 2) ? -1.0f : 0.0f;

    // ---- W_hh row as 32 packed fp16 pairs (32 VGPRs, pinned) ----
    int w2[32];
    {
        const float* rowp = W_hh + (size_t)row * H_SZ;
        #pragma unroll
        for (int j = 0; j < 32; ++j)
            w2[j] = as_i(__builtin_amdgcn_cvt_pkrtz(rowp[2*j]   * scale,
                                                    rowp[2*j+1] * scale));
    }
    #pragma unroll
    for (int k = 0; k < 32; k += 8)
        asm volatile("" : "+v"(w2[k+0]), "+v"(w2[k+1]), "+v"(w2[k+2]), "+v"(w2[k+3]),
                          "+v"(w2[k+4]), "+v"(w2[k+5]), "+v"(w2[k+6]), "+v"(w2[k+7]));

    // W_ih row packed (scaled), combined bias (scaled)
    const int wi01 = as_i(__builtin_amdgcn_cvt_pkrtz(W_ih[row*3+0] * scale,
                                                     W_ih[row*3+1] * scale));
    const int wi2p = as_i(__builtin_amdgcn_cvt_pkrtz(W_ih[row*3+2] * scale, 0.0f));
    const float bg = (b_ih[row] + b_hh[row]) * scale;

    float cA = 0.0f, cB = 0.0f;         // unit u cell state (quad-redundant)
    int next_cp = T_PAST_ + WSPF_ - 1;
    int cp_k = 0;

    __syncthreads();

    for (int t = 0; t < T_TOT; ++t) {
        // ---- dots for both elements: uniform b128 reads + 32 fdot2 each ----
        const int4* hA4 = (const int4*)h2buf[0][t & 1];
        const int4* hB4 = (const int4*)h2buf[1][t & 1];
        float aA0 = bg, aA1 = 0.f, aA2 = 0.f, aA3 = 0.f;
        float aB0 = bg, aB1 = 0.f, aB2 = 0.f, aB3 = 0.f;
        #pragma unroll
        for (int q = 0; q < 8; ++q) {
            int4 pv = hA4[q];
            aA0 = dot2_(w2[4*q+0], pv.x, aA0);
            aA1 = dot2_(w2[4*q+1], pv.y, aA1);
            aA2 = dot2_(w2[4*q+2], pv.z, aA2);
            aA3 = dot2_(w2[4*q+3], pv.w, aA3);
        }
        #pragma unroll
        for (int q = 0; q < 8; ++q) {
            int4 pv = hB4[q];
            aB0 = dot2_(w2[4*q+0], pv.x, aB0);
            aB1 = dot2_(w2[4*q+1], pv.y, aB1);
            aB2 = dot2_(w2[4*q+2], pv.z, aB2);
            aB3 = dot2_(w2[4*q+3], pv.w, aB3);
        }
        aA1 = dot2_(wi01, x2_lds[0][2*t], aA1);
        aA2 = dot2_(wi2p, x2_lds[0][2*t+1], aA2);
        aB1 = dot2_(wi01, x2_lds[1][2*t], aB1);
        aB2 = dot2_(wi2p, x2_lds[1][2*t+1], aB2);
        float accA = (aA0 + aA1) + (aA2 + aA3);
        float accB = (aB0 + aB1) + (aB2 + aB3);

        // sigmoid / tanh via raw exp2 (scale pre-folded)
        float gvA = fmaf(aa, rcp_(1.0f + exp2_(-accA)), bb);
        float gvB = fmaf(aa, rcp_(1.0f + exp2_(-accB)), bb);

        // ---- quad gather (DPP), update both elements in-lane ----
        float giA = quadb_<0x00>(gvA), gfA = quadb_<0x55>(gvA);
        float ggA = quadb_<0xAA>(gvA), goA = quadb_<0xFF>(gvA);
        float giB = quadb_<0x00>(gvB), gfB = quadb_<0x55>(gvB);
        float ggB = quadb_<0xAA>(gvB), goB = quadb_<0xFF>(gvB);
        cA = fmaf(gfA, cA, giA * ggA);
        cB = fmaf(gfB, cB, giB * ggB);
        float hA = goA * tanh2_(cA);
        float hB = goB * tanh2_(cB);

        // ---- publish h directly as fp16 (no swizzle/pack on the chain) ----
        if (g == 0) {
            h2buf[0][(t + 1) & 1][u] = (__fp16)hA;
            h2buf[1][(t + 1) & 1][u] = (__fp16)hB;
        }
        __syncthreads();                // h(t) visible to all waves

        if (t == next_cp) {             // block-uniform: stash checkpoint h
            if (tid < 2 * H_SZ)
                stash[tid >> 6][cp_k][tid & 63] = h2buf[tid >> 6][(t + 1) & 1][tid & 63];
            next_cp += WSPF_;
            ++cp_k;
        }
    }

    // ---- all 100 projections once, off the recurrent loop ----
    __syncthreads();
    for (int idx = tid; idx < 2 * FUT_SEQ * H_SZ; idx += NTHREADS) {
        int e = (idx >= FUT_SEQ * H_SZ);
        int r = idx - e * (FUT_SEQ * H_SZ);
        int k = r >> 6, j = r & 63;
        const int* hs = (const int*)&stash[e][k][0];   // 32 packed pairs
        float p = b_proj[j];
        #pragma unroll 8
        for (int m = 0; m < 32; ++m)
            p = dot2_(wp_lds[j * 33 + m], hs[m], p);
        out[((size_t)(e ? b + NBLK : b) * FUT_SEQ + k) * H_SZ + j] = p;
    }
}

extern "C" void kernel_launch(void* const* d_in, const int* in_sizes, int n_in,
                              void* d_out, int out_size, void* d_ws, size_t ws_size,
                              hipStream_t stream) {
    const float* wave_input  = (const float*)d_in[0];
    const float* wave_future = (const float*)d_in[1];
    const float* W_ih        = (const float*)d_in[2];
    const float* W_hh        = (const float*)d_in[3];
    const float* b_ih        = (const float*)d_in[4];
    const float* b_hh        = (const float*)d_in[5];
    const float* W_proj      = (const float*)d_in[6];
    const float* b_proj      = (const float*)d_in[7];
    float* out               = (float*)d_out;

    lstm_fused_kernel<<<NBLK, NTHREADS, 0, stream>>>(
        wave_input, wave_future, W_ih, W_hh, b_ih, b_hh, W_proj, b_proj, out);
}